// Round 9
// baseline (430.304 us; speedup 1.0000x reference)
//
#include <hip/hip_runtime.h>

#define C 16
#define NIMG 24
#define H 96
#define W 192
#define PX (H*W)            // 18432
#define LOG2E 1.44269504088896f

typedef float v2f  __attribute__((ext_vector_type(2)));
typedef float v4f  __attribute__((ext_vector_type(4)));
typedef float v8f  __attribute__((ext_vector_type(8)));
typedef float v16f __attribute__((ext_vector_type(16)));

// workspace float offsets
#define QP_OFF 0                                // float2 [n][px]
#define KP_OFF (NIMG*PX*2)                      // float2 [n][px]
#define VP_OFF (2*NIMG*PX*2)                    // v4f [n][h][c4][w]
#define X1_OFF (VP_OFF + NIMG*PX*C)             // 8847360
#define CMAX_OFF (X1_OFF + NIMG*C*PX)           // 15925248
#define RMAX_OFF (CMAX_OFF + NIMG*2*W)          // +9216

__global__ __launch_bounds__(256)
void qkv_kernel(const float* __restrict__ x, long xn_s, long xc_s,
                const float* __restrict__ qw, const float* __restrict__ qb,
                const float* __restrict__ kw, const float* __restrict__ kb,
                const float* __restrict__ vw, const float* __restrict__ vb,
                float2* __restrict__ Qp, float2* __restrict__ Kp,
                float4* __restrict__ Vp)
{
    __shared__ float wq[2*C+2], wk[2*C+2], wv[C*C+C];
    int tid = threadIdx.x;
    if (tid < 2*C) { wq[tid] = qw[tid]; wk[tid] = kw[tid]; }
    if (tid < 2)   { wq[2*C+tid] = qb[tid]; wk[2*C+tid] = kb[tid]; }
    if (tid < C*C) wv[tid] = vw[tid];
    if (tid < C)   wv[C*C+tid] = vb[tid];
    __syncthreads();

    int id = blockIdx.x*256 + tid;        // 0 .. 442367
    int n  = id / PX;
    int p  = id - n*PX;
    int h  = p / W;
    int w  = p - h*W;
    const float* xp = x + (long)n*xn_s + p;

    float xv[C];
    #pragma unroll
    for (int c = 0; c < C; c++) xv[c] = xp[(long)c*xc_s];

    float q0 = wq[2*C], q1 = wq[2*C+1];
    float k0 = wk[2*C], k1 = wk[2*C+1];
    #pragma unroll
    for (int c = 0; c < C; c++) {
        q0 += wq[c]*xv[c];   q1 += wq[C+c]*xv[c];
        k0 += wk[c]*xv[c];   k1 += wk[C+c]*xv[c];
    }
    Qp[id] = make_float2(q0, q1);
    Kp[id] = make_float2(k0, k1);

    float vv[C];
    #pragma unroll
    for (int o = 0; o < C; o++) {
        float a = wv[C*C+o];
        #pragma unroll
        for (int c = 0; c < C; c++) a += wv[o*C+c]*xv[c];
        vv[o] = a;
    }
    // layout: V[n][h][c4][w], float4 = channels 4c4..4c4+3 of pixel (h,w)
    #pragma unroll
    for (int c4 = 0; c4 < 4; c4++)
        Vp[(((long)n*H + h)*4 + c4)*W + w] =
            make_float4(vv[c4*4+0], vv[c4*4+1], vv[c4*4+2], vv[c4*4+3]);
}

__global__ __launch_bounds__(192)
void stats_kernel(const float2* __restrict__ Kp,
                  float* __restrict__ cmax, float* __restrict__ rmax)
{
    int n = blockIdx.x;
    int tid = threadIdx.x;
    const float2* Kpn = Kp + n*PX;

    float c0 = 0.f, c1 = 0.f;
    for (int h = 0; h < H; h++) {
        float2 k = Kpn[h*W + tid];
        c0 = fmaxf(c0, fabsf(k.x));
        c1 = fmaxf(c1, fabsf(k.y));
    }
    cmax[n*2*W + tid]     = c0;
    cmax[n*2*W + W + tid] = c1;

    if (tid < H) {
        float r0 = 0.f, r1 = 0.f;
        for (int j = 0; j < W; j++) {
            float2 k = Kpn[tid*W + j];
            r0 = fmaxf(r0, fabsf(k.x));
            r1 = fmaxf(r1, fabsf(k.y));
        }
        rmax[n*2*H + tid]     = r0;
        rmax[n*2*H + H + tid] = r1;
    }
}

__global__ __launch_bounds__(384, 4)
void attn_kernel(const float2* __restrict__ Qp, const float2* __restrict__ Kp,
                 const v4f* __restrict__ Vp,
                 const float* __restrict__ cmax, const float* __restrict__ rmax,
                 const float* __restrict__ xres, long xn_s, long xc_s,
                 float* __restrict__ out, long on_s, long oc_s,
                 const float* __restrict__ gamma_p)
{
    // bijective XCD swizzle: nwg = NIMG*(H/4) = 576, divisible by 8
    const int chunk = (NIMG*(H/4)) / 8;    // 72
    int bid = blockIdx.x;
    int swz = (bid & 7)*chunk + (bid >> 3);
    int n   = swz / (H/4);
    int h0  = (swz - n*(H/4)) * 4;
    int tid = threadIdx.x;
    int gi  = tid / 192;                   // wave-uniform (3 waves per group)
    int w   = tid - gi*192;                // 0..191
    int hr0 = h0 + 2*gi;
    int hr1 = hr0 + 1;

    const float2* Qpn = Qp + n*PX;
    const float2* Kpn = Kp + n*PX;
    const v4f*    Vpn = Vp + (long)n*PX*4;   // [h][c4][w]

    // q (log2 domain) and softmax shift bound m for both rows
    float c0 = cmax[n*2*W + w], c1 = cmax[n*2*W + W + w];
    float qx0, qy0, m0, qx1, qy1, m1;
    {
        float2 qq = Qpn[hr0*W + w];
        qx0 = qq.x * LOG2E;  qy0 = qq.y * LOG2E;
        float r0 = rmax[n*2*H + hr0], r1 = rmax[n*2*H + H + hr0];
        m0 = fmaxf(fabsf(qx0)*c0 + fabsf(qy0)*c1, fabsf(qx0)*r0 + fabsf(qy0)*r1);
    }
    {
        float2 qq = Qpn[hr1*W + w];
        qx1 = qq.x * LOG2E;  qy1 = qq.y * LOG2E;
        float r0 = rmax[n*2*H + hr1], r1 = rmax[n*2*H + H + hr1];
        m1 = fmaxf(fabsf(qx1)*c0 + fabsf(qy1)*c1, fabsf(qx1)*r0 + fabsf(qy1)*r1);
    }

    v2f acc0[8] = {}, acc1[8] = {};
    float s0 = 0.f, s1 = 0.f;

    // ---- column (H) part: coalesced global, 2 rows per load, diag masked ----
    {
        const float2* kp = Kpn + w;
        const v4f*    vp = Vpn + w;
        #pragma unroll 2
        for (int j = 0; j < H; j++) {
            float2 k = *kp;
            v4f a0 = vp[0*W], a1 = vp[1*W], a2 = vp[2*W], a3 = vp[3*W];
            float e0 = qx0*k.x + qy0*k.y;
            float p0 = __builtin_amdgcn_exp2f(e0 - m0);
            p0 = (j == hr0) ? 0.0f : p0;
            float e1 = qx1*k.x + qy1*k.y;
            float p1 = __builtin_amdgcn_exp2f(e1 - m1);
            p1 = (j == hr1) ? 0.0f : p1;
            s0 += p0;  s1 += p1;
            v2f pv0 = {p0, p0}, pv1 = {p1, p1};
            v2f t;
            t = (v2f){a0.x, a0.y};  acc0[0] += t*pv0;  acc1[0] += t*pv1;
            t = (v2f){a0.z, a0.w};  acc0[1] += t*pv0;  acc1[1] += t*pv1;
            t = (v2f){a1.x, a1.y};  acc0[2] += t*pv0;  acc1[2] += t*pv1;
            t = (v2f){a1.z, a1.w};  acc0[3] += t*pv0;  acc1[3] += t*pv1;
            t = (v2f){a2.x, a2.y};  acc0[4] += t*pv0;  acc1[4] += t*pv1;
            t = (v2f){a2.z, a2.w};  acc0[5] += t*pv0;  acc1[5] += t*pv1;
            t = (v2f){a3.x, a3.y};  acc0[6] += t*pv0;  acc1[6] += t*pv1;
            t = (v2f){a3.z, a3.w};  acc0[7] += t*pv0;  acc1[7] += t*pv1;
            kp += W;
            vp += 4*W;
        }
    }

    // ---- row (W) part: wave-uniform scalar loads (s_load), no LDS ----
    auto row_pass = [&](int hr, float qx, float qy, float mm, v2f* acc, float& s) {
        int hru = __builtin_amdgcn_readfirstlane(hr);
        const float* vr = (const float*)Vpn + (long)hru*16*W;  // [c4][w] floats
        const float* kr = (const float*)Kpn + (long)hru*2*W;
        for (int jc = 0; jc < W; jc += 4) {
            v16f B0 = *(const v16f*)(vr + 0*4*W + jc*4);
            v16f B1 = *(const v16f*)(vr + 1*4*W + jc*4);
            v16f B2 = *(const v16f*)(vr + 2*4*W + jc*4);
            v16f B3 = *(const v16f*)(vr + 3*4*W + jc*4);
            v8f  Kc = *(const v8f*)(kr + jc*2);
            #pragma unroll
            for (int jj = 0; jj < 4; jj++) {
                float e = qx*Kc[2*jj] + qy*Kc[2*jj+1];
                float p = __builtin_amdgcn_exp2f(e - mm);
                s += p;
                v2f pv = {p, p};
                acc[0] += (v2f){B0[4*jj+0], B0[4*jj+1]} * pv;
                acc[1] += (v2f){B0[4*jj+2], B0[4*jj+3]} * pv;
                acc[2] += (v2f){B1[4*jj+0], B1[4*jj+1]} * pv;
                acc[3] += (v2f){B1[4*jj+2], B1[4*jj+3]} * pv;
                acc[4] += (v2f){B2[4*jj+0], B2[4*jj+1]} * pv;
                acc[5] += (v2f){B2[4*jj+2], B2[4*jj+3]} * pv;
                acc[6] += (v2f){B3[4*jj+0], B3[4*jj+1]} * pv;
                acc[7] += (v2f){B3[4*jj+2], B3[4*jj+3]} * pv;
            }
        }
    };
    row_pass(hr0, qx0, qy0, m0, acc0, s0);
    row_pass(hr1, qx1, qy1, m1, acc1, s1);

    // ---- epilogue: gamma*(acc/s) + residual for both rows ----
    float g = gamma_p[0];
    {
        float inv = 1.0f / s0;
        #pragma unroll
        for (int c = 0; c < C; c++) {
            float tot = acc0[c>>1][c&1];
            float res = g*(tot*inv)
                      + xres[(long)n*xn_s + (long)c*xc_s + hr0*W + w];
            out[(long)n*on_s + (long)c*oc_s + hr0*W + w] = res;
        }
    }
    {
        float inv = 1.0f / s1;
        #pragma unroll
        for (int c = 0; c < C; c++) {
            float tot = acc1[c>>1][c&1];
            float res = g*(tot*inv)
                      + xres[(long)n*xn_s + (long)c*xc_s + hr1*W + w];
            out[(long)n*on_s + (long)c*oc_s + hr1*W + w] = res;
        }
    }
}

extern "C" void kernel_launch(void* const* d_in, const int* in_sizes, int n_in,
                              void* d_out, int out_size, void* d_ws, size_t ws_size,
                              hipStream_t stream) {
    const float* cost = (const float*)d_in[0];   // (1,16,24,96,192)
    const float* q_w  = (const float*)d_in[1];
    const float* q_b  = (const float*)d_in[2];
    const float* k_w  = (const float*)d_in[3];
    const float* k_b  = (const float*)d_in[4];
    const float* v_w  = (const float*)d_in[5];
    const float* v_b  = (const float*)d_in[6];
    const float* gamma= (const float*)d_in[7];
    float* out = (float*)d_out;
    float* ws  = (float*)d_ws;

    float2* Qp = (float2*)(ws + QP_OFF);
    float2* Kp = (float2*)(ws + KP_OFF);
    float4* Vp = (float4*)(ws + VP_OFF);
    float*  X1 = ws + X1_OFF;
    float*  cm = ws + CMAX_OFF;
    float*  rm = ws + RMAX_OFF;

    const int qkv_blocks  = (NIMG*PX)/256;   // 1728
    const int attn_blocks = NIMG*(H/4);      // 576

    // pass 1: x = cost_volume, layout [c][n][h][w] (n stride PX, c stride 24*PX)
    qkv_kernel<<<qkv_blocks, 256, 0, stream>>>(
        cost, (long)PX, (long)NIMG*PX,
        q_w, q_b, k_w, k_b, v_w, v_b, Qp, Kp, Vp);
    stats_kernel<<<NIMG, 192, 0, stream>>>(Kp, cm, rm);
    attn_kernel<<<attn_blocks, 384, 0, stream>>>(
        Qp, Kp, (const v4f*)Vp, cm, rm,
        cost, (long)PX, (long)NIMG*PX,
        X1, (long)C*PX, (long)PX,
        gamma);

    // pass 2: x = X1 ([n][c][h][w]); final out layout [c][n][h][w]
    qkv_kernel<<<qkv_blocks, 256, 0, stream>>>(
        X1, (long)C*PX, (long)PX,
        q_w, q_b, k_w, k_b, v_w, v_b, Qp, Kp, Vp);
    stats_kernel<<<NIMG, 192, 0, stream>>>(Kp, cm, rm);
    attn_kernel<<<attn_blocks, 384, 0, stream>>>(
        Qp, Kp, (const v4f*)Vp, cm, rm,
        X1, (long)C*PX, (long)PX,
        out, (long)PX, (long)NIMG*PX,
        gamma);
}

// Round 10
// 335.919 us; speedup vs baseline: 1.2810x; 1.2810x over previous
//
#include <hip/hip_runtime.h>

#define C 16
#define NIMG 24
#define H 96
#define W 192
#define PX (H*W)            // 18432
#define LOG2E 1.44269504088896f

typedef float v2f  __attribute__((ext_vector_type(2)));
typedef float v4f  __attribute__((ext_vector_type(4)));
typedef float v8f  __attribute__((ext_vector_type(8)));

// workspace float offsets
#define QP_OFF 0                                // float2 [n][px]
#define KP_OFF (NIMG*PX*2)                      // float2 [n][px]
#define VP_OFF (2*NIMG*PX*2)                    // float4 [n][h][c4][w]
#define X1_OFF (VP_OFF + NIMG*PX*C)             // 8847360
#define CMAX_OFF (X1_OFF + NIMG*C*PX)           // 15925248
#define RMAX_OFF (CMAX_OFF + NIMG*2*W)          // +9216

__global__ __launch_bounds__(256)
void qkv_kernel(const float* __restrict__ x, long xn_s, long xc_s,
                const float* __restrict__ qw, const float* __restrict__ qb,
                const float* __restrict__ kw, const float* __restrict__ kb,
                const float* __restrict__ vw, const float* __restrict__ vb,
                float2* __restrict__ Qp, float2* __restrict__ Kp,
                float4* __restrict__ Vp)
{
    __shared__ float wq[2*C+2], wk[2*C+2], wv[C*C+C];
    int tid = threadIdx.x;
    if (tid < 2*C) { wq[tid] = qw[tid]; wk[tid] = kw[tid]; }
    if (tid < 2)   { wq[2*C+tid] = qb[tid]; wk[2*C+tid] = kb[tid]; }
    if (tid < C*C) wv[tid] = vw[tid];
    if (tid < C)   wv[C*C+tid] = vb[tid];
    __syncthreads();

    int id = blockIdx.x*256 + tid;        // 0 .. 442367
    int n  = id / PX;
    int p  = id - n*PX;
    int h  = p / W;
    int w  = p - h*W;
    const float* xp = x + (long)n*xn_s + p;

    float xv[C];
    #pragma unroll
    for (int c = 0; c < C; c++) xv[c] = xp[(long)c*xc_s];

    float q0 = wq[2*C], q1 = wq[2*C+1];
    float k0 = wk[2*C], k1 = wk[2*C+1];
    #pragma unroll
    for (int c = 0; c < C; c++) {
        q0 += wq[c]*xv[c];   q1 += wq[C+c]*xv[c];
        k0 += wk[c]*xv[c];   k1 += wk[C+c]*xv[c];
    }
    Qp[id] = make_float2(q0, q1);
    Kp[id] = make_float2(k0, k1);

    float vv[C];
    #pragma unroll
    for (int o = 0; o < C; o++) {
        float a = wv[C*C+o];
        #pragma unroll
        for (int c = 0; c < C; c++) a += wv[o*C+c]*xv[c];
        vv[o] = a;
    }
    // layout: V[n][h][c4][w], float4 = channels 4c4..4c4+3 of pixel (h,w)
    #pragma unroll
    for (int c4 = 0; c4 < 4; c4++)
        Vp[(((long)n*H + h)*4 + c4)*W + w] =
            make_float4(vv[c4*4+0], vv[c4*4+1], vv[c4*4+2], vv[c4*4+3]);
}

__global__ __launch_bounds__(192)
void stats_kernel(const float2* __restrict__ Kp,
                  float* __restrict__ cmax, float* __restrict__ rmax)
{
    int n = blockIdx.x;
    int tid = threadIdx.x;
    const float2* Kpn = Kp + n*PX;

    float c0 = 0.f, c1 = 0.f;
    for (int h = 0; h < H; h++) {
        float2 k = Kpn[h*W + tid];
        c0 = fmaxf(c0, fabsf(k.x));
        c1 = fmaxf(c1, fabsf(k.y));
    }
    cmax[n*2*W + tid]     = c0;
    cmax[n*2*W + W + tid] = c1;

    if (tid < H) {
        float r0 = 0.f, r1 = 0.f;
        for (int j = 0; j < W; j++) {
            float2 k = Kpn[tid*W + j];
            r0 = fmaxf(r0, fabsf(k.x));
            r1 = fmaxf(r1, fabsf(k.y));
        }
        rmax[n*2*H + tid]     = r0;
        rmax[n*2*H + H + tid] = r1;
    }
}

// one 2-j row chunk: B0..B3 = v8f (2 pixels x 4 ch per c4), Kc = v4f (2 pixels x k0,k1)
#define ROW_CHUNK(vr, kr, jb, qx, qy, mm, acc, s) do {                         \
    v8f B0 = *(const v8f*)((vr) + (0*W + (jb))*4);                             \
    v8f B1 = *(const v8f*)((vr) + (1*W + (jb))*4);                             \
    v8f B2 = *(const v8f*)((vr) + (2*W + (jb))*4);                             \
    v8f B3 = *(const v8f*)((vr) + (3*W + (jb))*4);                             \
    v4f Kc = *(const v4f*)((kr) + (jb)*2);                                     \
    _Pragma("unroll")                                                          \
    for (int jj = 0; jj < 2; jj++) {                                           \
        float e = (qx)*Kc[2*jj] + (qy)*Kc[2*jj+1];                             \
        float p = __builtin_amdgcn_exp2f(e - (mm));                            \
        (s) += p;                                                              \
        v2f pv = {p, p};                                                       \
        acc[0] += (v2f){B0[4*jj+0], B0[4*jj+1]} * pv;                          \
        acc[1] += (v2f){B0[4*jj+2], B0[4*jj+3]} * pv;                          \
        acc[2] += (v2f){B1[4*jj+0], B1[4*jj+1]} * pv;                          \
        acc[3] += (v2f){B1[4*jj+2], B1[4*jj+3]} * pv;                          \
        acc[4] += (v2f){B2[4*jj+0], B2[4*jj+1]} * pv;                          \
        acc[5] += (v2f){B2[4*jj+2], B2[4*jj+3]} * pv;                          \
        acc[6] += (v2f){B3[4*jj+0], B3[4*jj+1]} * pv;                          \
        acc[7] += (v2f){B3[4*jj+2], B3[4*jj+3]} * pv;                          \
    }                                                                          \
} while (0)

__global__ __launch_bounds__(384, 4)
void attn_kernel(const float2* __restrict__ Qp, const float2* __restrict__ Kp,
                 const v4f* __restrict__ Vp,
                 const float* __restrict__ cmax, const float* __restrict__ rmax,
                 const float* __restrict__ xres, long xn_s, long xc_s,
                 float* __restrict__ out, long on_s, long oc_s,
                 const float* __restrict__ gamma_p)
{
    // bijective XCD swizzle: nwg = NIMG*(H/4) = 576, divisible by 8
    const int chunk = (NIMG*(H/4)) / 8;    // 72
    int bid = blockIdx.x;
    int swz = (bid & 7)*chunk + (bid >> 3);
    int n   = swz / (H/4);
    int h0  = (swz - n*(H/4)) * 4;
    int tid = threadIdx.x;
    int gi  = tid / 192;                   // wave-uniform (3 waves per group)
    int w   = tid - gi*192;                // 0..191
    int hr0 = h0 + 2*gi;
    int hr1 = hr0 + 1;

    const float2* Qpn = Qp + n*PX;
    const float2* Kpn = Kp + n*PX;
    const v4f*    Vpn = Vp + (long)n*PX*4;   // [h][c4][w]

    // q (log2 domain) and softmax shift bound m for both rows
    float c0 = cmax[n*2*W + w], c1 = cmax[n*2*W + W + w];
    float qx0, qy0, m0, qx1, qy1, m1;
    {
        float2 qq = Qpn[hr0*W + w];
        qx0 = qq.x * LOG2E;  qy0 = qq.y * LOG2E;
        float r0 = rmax[n*2*H + hr0], r1 = rmax[n*2*H + H + hr0];
        m0 = fmaxf(fabsf(qx0)*c0 + fabsf(qy0)*c1, fabsf(qx0)*r0 + fabsf(qy0)*r1);
    }
    {
        float2 qq = Qpn[hr1*W + w];
        qx1 = qq.x * LOG2E;  qy1 = qq.y * LOG2E;
        float r0 = rmax[n*2*H + hr1], r1 = rmax[n*2*H + H + hr1];
        m1 = fmaxf(fabsf(qx1)*c0 + fabsf(qy1)*c1, fabsf(qx1)*r0 + fabsf(qy1)*r1);
    }

    v2f acc0[8] = {}, acc1[8] = {};
    float s0 = 0.f, s1 = 0.f;

    // wave-uniform row base pointers (force SGPR addressing -> s_load)
    int hu0 = __builtin_amdgcn_readfirstlane(hr0);
    int hu1 = __builtin_amdgcn_readfirstlane(hr1);
    const float* vrow0 = (const float*)Vpn + (long)hu0*4*W*4;   // [c4][w][4]
    const float* vrow1 = (const float*)Vpn + (long)hu1*4*W*4;
    const float* krow0 = (const float*)Kpn + (long)hu0*W*2;
    const float* krow1 = (const float*)Kpn + (long)hu1*W*2;

    // column carried pointers
    const float2* kp = Kpn + w;
    const v4f*    vp = Vpn + w;

    // fused loop: 48 iterations; each = 2 column j-steps + one 2-j row chunk
    // per row. Static unroll keeps acc0/acc1 register-resident (no runtime idx).
    for (int t = 0; t < 48; ++t) {
        int jb = t*4;                      // row chunk base for this round (4 js in 2 chunks)

        // ---- column step j = 2t (+ row0 chunk jb..jb+1) ----
        {
            int j = 2*t;
            float2 k = *kp;
            v4f a0 = vp[0*W], a1 = vp[1*W], a2 = vp[2*W], a3 = vp[3*W];
            ROW_CHUNK(vrow0, krow0, jb, qx0, qy0, m0, acc0, s0);
            float e0 = qx0*k.x + qy0*k.y;
            float p0 = __builtin_amdgcn_exp2f(e0 - m0);
            p0 = (j == hr0) ? 0.0f : p0;
            float e1 = qx1*k.x + qy1*k.y;
            float p1 = __builtin_amdgcn_exp2f(e1 - m1);
            p1 = (j == hr1) ? 0.0f : p1;
            s0 += p0;  s1 += p1;
            v2f pv0 = {p0, p0}, pv1 = {p1, p1};
            v2f x;
            x = (v2f){a0.x, a0.y};  acc0[0] += x*pv0;  acc1[0] += x*pv1;
            x = (v2f){a0.z, a0.w};  acc0[1] += x*pv0;  acc1[1] += x*pv1;
            x = (v2f){a1.x, a1.y};  acc0[2] += x*pv0;  acc1[2] += x*pv1;
            x = (v2f){a1.z, a1.w};  acc0[3] += x*pv0;  acc1[3] += x*pv1;
            x = (v2f){a2.x, a2.y};  acc0[4] += x*pv0;  acc1[4] += x*pv1;
            x = (v2f){a2.z, a2.w};  acc0[5] += x*pv0;  acc1[5] += x*pv1;
            x = (v2f){a3.x, a3.y};  acc0[6] += x*pv0;  acc1[6] += x*pv1;
            x = (v2f){a3.z, a3.w};  acc0[7] += x*pv0;  acc1[7] += x*pv1;
            kp += W;  vp += 4*W;
        }
        // ---- column step j = 2t+1 (+ row0 chunk jb+2..jb+3, row1 chunks) ----
        {
            int j = 2*t + 1;
            float2 k = *kp;
            v4f a0 = vp[0*W], a1 = vp[1*W], a2 = vp[2*W], a3 = vp[3*W];
            ROW_CHUNK(vrow0, krow0, jb+2, qx0, qy0, m0, acc0, s0);
            ROW_CHUNK(vrow1, krow1, jb,   qx1, qy1, m1, acc1, s1);
            float e0 = qx0*k.x + qy0*k.y;
            float p0 = __builtin_amdgcn_exp2f(e0 - m0);
            p0 = (j == hr0) ? 0.0f : p0;
            float e1 = qx1*k.x + qy1*k.y;
            float p1 = __builtin_amdgcn_exp2f(e1 - m1);
            p1 = (j == hr1) ? 0.0f : p1;
            s0 += p0;  s1 += p1;
            v2f pv0 = {p0, p0}, pv1 = {p1, p1};
            v2f x;
            x = (v2f){a0.x, a0.y};  acc0[0] += x*pv0;  acc1[0] += x*pv1;
            x = (v2f){a0.z, a0.w};  acc0[1] += x*pv0;  acc1[1] += x*pv1;
            x = (v2f){a1.x, a1.y};  acc0[2] += x*pv0;  acc1[2] += x*pv1;
            x = (v2f){a1.z, a1.w};  acc0[3] += x*pv0;  acc1[3] += x*pv1;
            x = (v2f){a2.x, a2.y};  acc0[4] += x*pv0;  acc1[4] += x*pv1;
            x = (v2f){a2.z, a2.w};  acc0[5] += x*pv0;  acc1[5] += x*pv1;
            x = (v2f){a3.x, a3.y};  acc0[6] += x*pv0;  acc1[6] += x*pv1;
            x = (v2f){a3.z, a3.w};  acc0[7] += x*pv0;  acc1[7] += x*pv1;
            kp += W;  vp += 4*W;
            ROW_CHUNK(vrow1, krow1, jb+2, qx1, qy1, m1, acc1, s1);
        }
    }

    // ---- epilogue: gamma*(acc/s) + residual for both rows ----
    float g = gamma_p[0];
    {
        float inv = 1.0f / s0;
        #pragma unroll
        for (int c = 0; c < C; c++) {
            float tot = acc0[c>>1][c&1];
            float res = g*(tot*inv)
                      + xres[(long)n*xn_s + (long)c*xc_s + hr0*W + w];
            out[(long)n*on_s + (long)c*oc_s + hr0*W + w] = res;
        }
    }
    {
        float inv = 1.0f / s1;
        #pragma unroll
        for (int c = 0; c < C; c++) {
            float tot = acc1[c>>1][c&1];
            float res = g*(tot*inv)
                      + xres[(long)n*xn_s + (long)c*xc_s + hr1*W + w];
            out[(long)n*on_s + (long)c*oc_s + hr1*W + w] = res;
        }
    }
}

extern "C" void kernel_launch(void* const* d_in, const int* in_sizes, int n_in,
                              void* d_out, int out_size, void* d_ws, size_t ws_size,
                              hipStream_t stream) {
    const float* cost = (const float*)d_in[0];   // (1,16,24,96,192)
    const float* q_w  = (const float*)d_in[1];
    const float* q_b  = (const float*)d_in[2];
    const float* k_w  = (const float*)d_in[3];
    const float* k_b  = (const float*)d_in[4];
    const float* v_w  = (const float*)d_in[5];
    const float* v_b  = (const float*)d_in[6];
    const float* gamma= (const float*)d_in[7];
    float* out = (float*)d_out;
    float* ws  = (float*)d_ws;

    float2* Qp = (float2*)(ws + QP_OFF);
    float2* Kp = (float2*)(ws + KP_OFF);
    float4* Vp = (float4*)(ws + VP_OFF);
    float*  X1 = ws + X1_OFF;
    float*  cm = ws + CMAX_OFF;
    float*  rm = ws + RMAX_OFF;

    const int qkv_blocks  = (NIMG*PX)/256;   // 1728
    const int attn_blocks = NIMG*(H/4);      // 576

    // pass 1: x = cost_volume, layout [c][n][h][w] (n stride PX, c stride 24*PX)
    qkv_kernel<<<qkv_blocks, 256, 0, stream>>>(
        cost, (long)PX, (long)NIMG*PX,
        q_w, q_b, k_w, k_b, v_w, v_b, Qp, Kp, Vp);
    stats_kernel<<<NIMG, 192, 0, stream>>>(Kp, cm, rm);
    attn_kernel<<<attn_blocks, 384, 0, stream>>>(
        Qp, Kp, (const v4f*)Vp, cm, rm,
        cost, (long)PX, (long)NIMG*PX,
        X1, (long)C*PX, (long)PX,
        gamma);

    // pass 2: x = X1 ([n][c][h][w]); final out layout [c][n][h][w]
    qkv_kernel<<<qkv_blocks, 256, 0, stream>>>(
        X1, (long)C*PX, (long)PX,
        q_w, q_b, k_w, k_b, v_w, v_b, Qp, Kp, Vp);
    stats_kernel<<<NIMG, 192, 0, stream>>>(Kp, cm, rm);
    attn_kernel<<<attn_blocks, 384, 0, stream>>>(
        Qp, Kp, (const v4f*)Vp, cm, rm,
        X1, (long)C*PX, (long)PX,
        out, (long)PX, (long)NIMG*PX,
        gamma);
}